// Round 2
// baseline (743.279 us; speedup 1.0000x reference)
//
#include <hip/hip_runtime.h>
#include <stdint.h>

#define DIN 512
#define DOUT 512

typedef short bf16x8 __attribute__((ext_vector_type(8)));
typedef float floatx4 __attribute__((ext_vector_type(4)));
typedef float f32x4 __attribute__((ext_vector_type(4)));

static __device__ __forceinline__ ushort f2bf(float f) {
  uint32_t u = __float_as_uint(f);
  u += 0x7FFFu + ((u >> 16) & 1u);   // RTNE; values are finite/normal here
  return (ushort)(u >> 16);
}

// async global->LDS, 16B per lane; LDS dest is wave-uniform base + lane*16
static __device__ __forceinline__ void gload16(const ushort* g, ushort* l) {
  __builtin_amdgcn_global_load_lds(
      (const __attribute__((address_space(1))) unsigned int*)g,
      (__attribute__((address_space(3))) unsigned int*)l, 16, 0, 0);
}

// ---------------- fused: degcount(+rank) | logmap0+bf16 | W->bf16 ----------------
__global__ __launch_bounds__(256) void fused1_kernel(
    const float* __restrict__ x, ushort* __restrict__ tanb,
    const float* __restrict__ W, ushort* __restrict__ Wbf,
    const int* __restrict__ dst, int* __restrict__ degi,
    ushort* __restrict__ rank, int N, int E) {
  int bid = blockIdx.x;
  int degB = (E + 255) >> 8;
  if (bid < degB) {                      // degree count + per-edge rank
    int e = bid * 256 + threadIdx.x;
    if (e < E) {
      int r = atomicAdd(&degi[dst[e]], 1);
      rank[e] = (ushort)r;               // coalesced 2B write; deg max << 64K
    }
    return;
  }
  bid -= degB;
  int logB = (N + 3) >> 2;
  if (bid < logB) {                      // logmap0 + cast (memory-bound)
    int row = bid * 4 + (threadIdx.x >> 6);
    if (row >= N) return;
    int lane = threadIdx.x & 63;
    const f32x4* xr = (const f32x4*)(x + (size_t)row * DIN);
    f32x4 v0 = __builtin_nontemporal_load(xr + lane * 2);      // x read once
    f32x4 v1 = __builtin_nontemporal_load(xr + lane * 2 + 1);
    float ss = v0[0]*v0[0] + v0[1]*v0[1] + v0[2]*v0[2] + v0[3]*v0[3] +
               v1[0]*v1[0] + v1[1]*v1[1] + v1[2]*v1[2] + v1[3]*v1[3];
#pragma unroll
    for (int m = 32; m >= 1; m >>= 1) ss += __shfl_xor(ss, m, 64);
    float n = sqrtf(ss);
    float nc = fminf(fmaxf(n, 1e-7f), 1.0f - 1e-7f);
    float scale = atanhf(nc) / nc;
    union { ushort s[8]; uint4 v; } o;
    o.s[0] = f2bf(v0[0] * scale); o.s[1] = f2bf(v0[1] * scale);
    o.s[2] = f2bf(v0[2] * scale); o.s[3] = f2bf(v0[3] * scale);
    o.s[4] = f2bf(v1[0] * scale); o.s[5] = f2bf(v1[1] * scale);
    o.s[6] = f2bf(v1[2] * scale); o.s[7] = f2bf(v1[3] * scale);
    *(uint4*)(tanb + (size_t)row * DIN + lane * 8) = o.v;
    return;
  }
  bid -= logB;                           // W fp32 -> bf16 (256 blocks)
  int i = bid * 1024 + threadIdx.x * 4;
  float4 w4 = *(const float4*)(W + i);
  ushort4 o4;
  o4.x = f2bf(w4.x); o4.y = f2bf(w4.y); o4.z = f2bf(w4.z); o4.w = f2bf(w4.w);
  *(ushort4*)(Wbf + i) = o4;
}

// ---------------- single-launch exclusive scan (one 1024-thread block) ----------
__global__ __launch_bounds__(1024) void scanall_kernel(const int* __restrict__ degi,
                                                       int* __restrict__ offs, int N) {
  __shared__ int s[1024];
  int tx = threadIdx.x;
  int chunk = (N + 1023) >> 10;
  chunk = (chunk + 3) & ~3;              // int4-friendly
  int lo = tx * chunk;
  int hi = lo + chunk; if (hi > N) hi = N;
  int sum = 0;
  int i = lo;
  for (; i + 4 <= hi; i += 4) {
    int4 v = *(const int4*)(degi + i);
    sum += v.x + v.y + v.z + v.w;
  }
  for (; i < hi; i++) sum += degi[i];
  s[tx] = sum;
  __syncthreads();
#pragma unroll
  for (int d = 1; d < 1024; d <<= 1) {
    int t = (tx >= d) ? s[tx - d] : 0;
    __syncthreads();
    s[tx] += t;
    __syncthreads();
  }
  int base = s[tx] - sum;                // exclusive prefix of this chunk
  for (i = lo; i < hi; i++) {
    int v = degi[i];
    offs[i] = base;
    base += v;
  }
}

// ---------------- GEMM (m97 structure) + atomic-free filladj merged ----------------
// Hb[m][n] = bf16( sum_k tan[m][k]*W[n][k] + b[n] )
// BM=128 BN=128 BK=64; 4 waves, 64x64 each; gload_lds16 staging with
// both-sides XOR swizzle; C staged through LDS for coalesced uint4 stores.
__global__ __launch_bounds__(256) void gemmfill_kernel(
    const ushort* __restrict__ A, const ushort* __restrict__ Bw,
    const float* __restrict__ bias, ushort* __restrict__ Hb, int M,
    const int* __restrict__ src, const int* __restrict__ dst,
    const int* __restrict__ offs, const ushort* __restrict__ rank,
    int* __restrict__ adj, int E, int FB) {
  __shared__ __align__(16) ushort smem[16384];  // As 16KB | Bs 16KB ; reused as Cs
  int bid = blockIdx.x;
  if (bid < FB) {                        // filladj: pure scatter, no atomics
    int e = bid * 256 + threadIdx.x;
    if (e < E) {
      int d = dst[e];
      adj[offs[d] + (int)rank[e]] = src[e];
    }
    return;
  }
  bid -= FB;
  // XCD-grouping map (bijective, m204): raw id -> work id so the 4 blocks
  // sharing one A-tile all land on the same XCD's L2.
  int NB = (int)gridDim.x - FB;
  int q = NB >> 3, r = NB & 7;
  int xcd = bid & 7, off = bid >> 3;
  int w = (xcd < r) ? xcd * (q + 1) + off : r * (q + 1) + (xcd - r) * q + off;
  int n0 = (w & 3) * 128;
  int m0 = (w >> 2) * 128;

  ushort* As = smem;
  ushort* Bs = smem + 8192;
  int tid = threadIdx.x;
  int wave = tid >> 6, lane = tid & 63;
  int wm = (wave >> 1) * 64, wn = (wave & 1) * 64;
  int fr = lane & 15, fq = lane >> 4;
  int rsub = lane >> 3;                          // 0..7 (row within 8-row group)
  int ksw = ((lane & 7) ^ rsub) * 8;             // inverse-swizzled k element offset

  floatx4 acc[4][4] = {};

  for (int k0 = 0; k0 < DIN; k0 += 64) {
#pragma unroll
    for (int i = 0; i < 4; i++) {
      int g = wave * 4 + i;                      // 8-row group 0..15
      int ra = g * 8 + rsub;                     // tile row 0..127
      int gm = m0 + ra; if (gm >= M) gm = M - 1; // clamp tail rows
      gload16(A + (size_t)gm * DIN + k0 + ksw, As + g * 512);
      gload16(Bw + (size_t)(n0 + ra) * DIN + k0 + ksw, Bs + g * 512);
    }
    __syncthreads();                             // vmcnt(0) drain + barrier
#pragma unroll
    for (int kk = 0; kk < 2; kk++) {
      bf16x8 af[4], bg[4];
#pragma unroll
      for (int t = 0; t < 4; t++) {
        int ra = wm + t * 16 + fr;
        af[t] = *(const bf16x8*)(As + ra * 64 + (((kk * 4 + fq) ^ (ra & 7)) << 3));
        int rb = wn + t * 16 + fr;
        bg[t] = *(const bf16x8*)(Bs + rb * 64 + (((kk * 4 + fq) ^ (rb & 7)) << 3));
      }
#pragma unroll
      for (int mt = 0; mt < 4; mt++)
#pragma unroll
        for (int nt = 0; nt < 4; nt++)
          acc[mt][nt] = __builtin_amdgcn_mfma_f32_16x16x32_bf16(
              af[mt], bg[nt], acc[mt][nt], 0, 0, 0);
    }
    __syncthreads();
  }

  // epilogue: bias + bf16 -> swizzled LDS C-tile -> coalesced 16B stores
  int rq = fq * 4;
#pragma unroll
  for (int nt = 0; nt < 4; nt++) {
    int col = wn + nt * 16 + fr;
    float bb = bias[n0 + col];
    int c16 = col >> 3;
#pragma unroll
    for (int mt = 0; mt < 4; mt++) {
#pragma unroll
      for (int rr = 0; rr < 4; rr++) {
        int row = wm + mt * 16 + rq + rr;
        smem[row * 128 + (((c16 ^ (row & 7)) << 3) | (col & 7))] =
            f2bf(acc[mt][nt][rr] + bb);
      }
    }
  }
  __syncthreads();
#pragma unroll
  for (int p = 0; p < 8; p++) {
    int idx = p * 256 + tid;
    int row = idx >> 4, cc = idx & 15;
    uint4 v = *(const uint4*)(smem + row * 128 + ((cc ^ (row & 7)) << 3));
    int gm = m0 + row;
    if (gm < M) *(uint4*)(Hb + (size_t)gm * DOUT + n0 + cc * 8) = v;
  }
}

// ---------------- aggregate + mean + expmap0 (one wave per node) ----------------
static __device__ __forceinline__ void accum8(float* acc, uint4 v) {
  acc[0] += __uint_as_float(v.x << 16); acc[1] += __uint_as_float(v.x & 0xFFFF0000u);
  acc[2] += __uint_as_float(v.y << 16); acc[3] += __uint_as_float(v.y & 0xFFFF0000u);
  acc[4] += __uint_as_float(v.z << 16); acc[5] += __uint_as_float(v.z & 0xFFFF0000u);
  acc[6] += __uint_as_float(v.w << 16); acc[7] += __uint_as_float(v.w & 0xFFFF0000u);
}

__global__ __launch_bounds__(256) void aggregate_kernel(const ushort* __restrict__ hb,
                                                        const int* __restrict__ adj,
                                                        const int* __restrict__ offs,
                                                        const int* __restrict__ degi,
                                                        float* __restrict__ out, int N) {
  int row = blockIdx.x * 4 + (threadIdx.x >> 6);
  if (row >= N) return;
  int lane = threadIdx.x & 63;
  int dg = degi[row];
  int base = offs[row];
  float acc[8] = {0.f, 0.f, 0.f, 0.f, 0.f, 0.f, 0.f, 0.f};
  int j = 0;
  for (; j + 8 <= dg; j += 8) {           // 8 gathers in flight
    int av = adj[base + j + (lane & 7)];  // one load, broadcast via readlane
    uint4 v[8];
#pragma unroll
    for (int qq = 0; qq < 8; qq++) {
      int s = __builtin_amdgcn_readlane(av, qq);
      v[qq] = *(const uint4*)(hb + (size_t)s * DOUT + lane * 8);
    }
#pragma unroll
    for (int qq = 0; qq < 8; qq++) accum8(acc, v[qq]);
  }
  for (; j + 4 <= dg; j += 4) {
    int av = adj[base + j + (lane & 3)];
    uint4 v[4];
#pragma unroll
    for (int qq = 0; qq < 4; qq++) {
      int s = __builtin_amdgcn_readlane(av, qq);
      v[qq] = *(const uint4*)(hb + (size_t)s * DOUT + lane * 8);
    }
#pragma unroll
    for (int qq = 0; qq < 4; qq++) accum8(acc, v[qq]);
  }
  for (; j < dg; j++) {
    int s = __builtin_amdgcn_readfirstlane(adj[base + j]);
    uint4 a = *(const uint4*)(hb + (size_t)s * DOUT + lane * 8);
    accum8(acc, a);
  }
  float inv = 1.0f / fmaxf((float)dg, 1.0f);
  float ss = 0.f;
#pragma unroll
  for (int k = 0; k < 8; k++) ss += acc[k] * acc[k];
#pragma unroll
  for (int m = 32; m >= 1; m >>= 1) ss += __shfl_xor(ss, m, 64);
  float n = fmaxf(inv * sqrtf(ss), 1e-7f);   // ||mean||, clamped like reference
  float sc = tanhf(n) / n * inv;
  f32x4 o0 = {acc[0] * sc, acc[1] * sc, acc[2] * sc, acc[3] * sc};
  f32x4 o1 = {acc[4] * sc, acc[5] * sc, acc[6] * sc, acc[7] * sc};
  float* orow = out + (size_t)row * DOUT + lane * 8;
  // nontemporal: out is write-once; keep L2/L3 for the hb gather working set
  __builtin_nontemporal_store(o0, (f32x4*)orow);
  __builtin_nontemporal_store(o1, (f32x4*)(orow + 4));
}

extern "C" void kernel_launch(void* const* d_in, const int* in_sizes, int n_in,
                              void* d_out, int out_size, void* d_ws, size_t ws_size,
                              hipStream_t stream) {
  const float* x = (const float*)d_in[0];
  const int* src = (const int*)d_in[1];
  const int* dst = (const int*)d_in[2];
  const float* W = (const float*)d_in[3];
  const float* b = (const float*)d_in[4];
  int N = in_sizes[0] / DIN;
  int E = in_sizes[1];
  float* out = (float*)d_out;

  // workspace layout
  char* ws = (char*)d_ws;
  size_t off = 0;
  ushort* Wbf = (ushort*)(ws + off); off += (size_t)DOUT * DIN * 2;
  ushort* tanb = (ushort*)(ws + off); off += (size_t)N * DIN * 2;
  ushort* hb = (ushort*)(ws + off); off += (size_t)N * DIN * 2;
  off = (off + 255) & ~(size_t)255;
  int* degi = (int*)(ws + off); off += (size_t)N * 4;
  off = (off + 255) & ~(size_t)255;
  int* offs = (int*)(ws + off); off += (size_t)N * 4;
  off = (off + 255) & ~(size_t)255;
  ushort* rank = (ushort*)(ws + off); off += (size_t)E * 2;
  off = (off + 255) & ~(size_t)255;
  int* adj = (int*)(ws + off); off += (size_t)E * 4;

  hipMemsetAsync(degi, 0, (size_t)N * 4, stream);

  int degB = (E + 255) >> 8;             // 3907
  int logB = (N + 3) >> 2;               // 25000
  int wB = (DOUT * DIN) / 1024;          // 256
  fused1_kernel<<<degB + logB + wB, 256, 0, stream>>>(x, tanb, W, Wbf, dst, degi,
                                                      rank, N, E);

  scanall_kernel<<<1, 1024, 0, stream>>>(degi, offs, N);

  int MB = (N + 127) >> 7;               // 782 m-tiles
  int FB = degB;                         // filladj blocks lead the gemm grid
  gemmfill_kernel<<<FB + 4 * MB, 256, 0, stream>>>(tanb, Wbf, b, hb, N,
                                                   src, dst, offs, rank, adj, E, FB);

  aggregate_kernel<<<(N + 3) / 4, 256, 0, stream>>>(hb, adj, offs, degi, out, N);
}

// Round 3
// 590.496 us; speedup vs baseline: 1.2587x; 1.2587x over previous
//
#include <hip/hip_runtime.h>
#include <stdint.h>

#define DIN 512
#define DOUT 512
#define HB 256        // histogram / coarse-scatter blocks
#define BKT_SH 7      // bucket = dst >> 7  (128 nodes per bucket; NB <= 1024 for N <= 131072)

typedef short bf16x8 __attribute__((ext_vector_type(8)));
typedef float floatx4 __attribute__((ext_vector_type(4)));
typedef float f32x4 __attribute__((ext_vector_type(4)));

static __device__ __forceinline__ ushort f2bf(float f) {
  uint32_t u = __float_as_uint(f);
  u += 0x7FFFu + ((u >> 16) & 1u);   // RTNE; values are finite/normal here
  return (ushort)(u >> 16);
}

// async global->LDS, 16B per lane; LDS dest is wave-uniform base + lane*16
static __device__ __forceinline__ void gload16(const ushort* g, ushort* l) {
  __builtin_amdgcn_global_load_lds(
      (const __attribute__((address_space(1))) unsigned int*)g,
      (__attribute__((address_space(3))) unsigned int*)l, 16, 0, 0);
}

// ---------------- fused: coarse-hist (LDS atomics) | logmap0+bf16 | W->bf16 ------
__global__ __launch_bounds__(256) void fused1_kernel(
    const float* __restrict__ x, ushort* __restrict__ tanb,
    const float* __restrict__ W, ushort* __restrict__ Wbf,
    const int* __restrict__ dst, int* __restrict__ ghist, int N, int E, int NB) {
  __shared__ int hist[1024];
  int bid = blockIdx.x;
  int tx = threadIdx.x;
  if (bid < HB) {                        // per-block private bucket histogram
    for (int i = tx; i < NB; i += 256) hist[i] = 0;
    __syncthreads();
    int EPB = (E + HB - 1) / HB;
    int e0 = bid * EPB;
    int e1 = e0 + EPB; if (e1 > E) e1 = E;
    for (int e = e0 + tx; e < e1; e += 256)
      atomicAdd(&hist[dst[e] >> BKT_SH], 1);       // LDS atomic — no L2 round trip
    __syncthreads();
    for (int b = tx; b < NB; b += 256)
      ghist[b * HB + bid] = hist[b];               // bucket-major for the scan
    return;
  }
  bid -= HB;
  int logB = (N + 3) >> 2;
  if (bid < logB) {                      // logmap0 + cast (memory-bound)
    int row = bid * 4 + (tx >> 6);
    if (row >= N) return;
    int lane = tx & 63;
    const f32x4* xr = (const f32x4*)(x + (size_t)row * DIN);
    f32x4 v0 = __builtin_nontemporal_load(xr + lane * 2);      // x read once
    f32x4 v1 = __builtin_nontemporal_load(xr + lane * 2 + 1);
    float ss = v0[0]*v0[0] + v0[1]*v0[1] + v0[2]*v0[2] + v0[3]*v0[3] +
               v1[0]*v1[0] + v1[1]*v1[1] + v1[2]*v1[2] + v1[3]*v1[3];
#pragma unroll
    for (int m = 32; m >= 1; m >>= 1) ss += __shfl_xor(ss, m, 64);
    float n = sqrtf(ss);
    float nc = fminf(fmaxf(n, 1e-7f), 1.0f - 1e-7f);
    float scale = atanhf(nc) / nc;
    union { ushort s[8]; uint4 v; } o;
    o.s[0] = f2bf(v0[0] * scale); o.s[1] = f2bf(v0[1] * scale);
    o.s[2] = f2bf(v0[2] * scale); o.s[3] = f2bf(v0[3] * scale);
    o.s[4] = f2bf(v1[0] * scale); o.s[5] = f2bf(v1[1] * scale);
    o.s[6] = f2bf(v1[2] * scale); o.s[7] = f2bf(v1[3] * scale);
    *(uint4*)(tanb + (size_t)row * DIN + lane * 8) = o.v;
    return;
  }
  bid -= logB;                           // W fp32 -> bf16 (256 blocks)
  int i = bid * 1024 + tx * 4;
  float4 w4 = *(const float4*)(W + i);
  ushort4 o4;
  o4.x = f2bf(w4.x); o4.y = f2bf(w4.y); o4.z = f2bf(w4.z); o4.w = f2bf(w4.w);
  *(ushort4*)(Wbf + i) = o4;
}

// ---------------- parallel 3-kernel exclusive scan over L = NB*HB ints ----------
__global__ __launch_bounds__(256) void scan1_kernel(const int* __restrict__ in,
                                                    int* __restrict__ outp,
                                                    int* __restrict__ bsum, int L) {
  __shared__ int s[256];
  int tx = threadIdx.x;
  int i = blockIdx.x * 256 + tx;
  int v = (i < L) ? in[i] : 0;
  s[tx] = v;
  __syncthreads();
#pragma unroll
  for (int d = 1; d < 256; d <<= 1) {
    int t = (tx >= d) ? s[tx - d] : 0;
    __syncthreads();
    s[tx] += t;
    __syncthreads();
  }
  if (i < L) outp[i] = s[tx] - v;            // exclusive within block
  if (tx == 255) bsum[blockIdx.x] = s[255];
}

__global__ __launch_bounds__(1024) void scan2_kernel(int* __restrict__ bsum, int B) {
  __shared__ int s[1024];
  int tx = threadIdx.x;
  int v = (tx < B) ? bsum[tx] : 0;
  s[tx] = v;
  __syncthreads();
#pragma unroll
  for (int d = 1; d < 1024; d <<= 1) {
    int t = (tx >= d) ? s[tx - d] : 0;
    __syncthreads();
    s[tx] += t;
    __syncthreads();
  }
  if (tx < B) bsum[tx] = s[tx] - v;
}

__global__ __launch_bounds__(256) void scan3_kernel(int* __restrict__ outp,
                                                    const int* __restrict__ bsum, int L) {
  int i = blockIdx.x * 256 + threadIdx.x;
  if (i < L) outp[i] += bsum[blockIdx.x];
}

// ---------------- coarse scatter: edges -> bucket-contiguous cs[] ---------------
// cs value packs (src << BKT_SH) | (dst & 127); valid for N < 2^25.
__global__ __launch_bounds__(256) void cscatter_kernel(
    const int* __restrict__ src, const int* __restrict__ dst,
    const int* __restrict__ gscan, uint32_t* __restrict__ cs, int E, int NB) {
  __shared__ int lcur[1024];
  int j = blockIdx.x, tx = threadIdx.x;
  for (int b = tx; b < NB; b += 256) lcur[b] = gscan[b * HB + j];
  __syncthreads();
  int EPB = (E + HB - 1) / HB;
  int e0 = j * EPB;
  int e1 = e0 + EPB; if (e1 > E) e1 = E;
  for (int e = e0 + tx; e < e1; e += 256) {
    int d = dst[e];
    int p = atomicAdd(&lcur[d >> BKT_SH], 1);      // LDS atomic with return
    cs[p] = ((uint32_t)src[e] << BKT_SH) | (uint32_t)(d & ((1 << BKT_SH) - 1));
  }
}

// ---------------- GEMM (m97 structure) + per-bucket fine counting sort ----------
// Hb[m][n] = bf16( sum_k tan[m][k]*W[n][k] + b[n] )
__global__ __launch_bounds__(256) void gemmfill_kernel(
    const ushort* __restrict__ A, const ushort* __restrict__ Bw,
    const float* __restrict__ bias, ushort* __restrict__ Hb, int M,
    const int* __restrict__ gscan, const uint32_t* __restrict__ cs,
    int* __restrict__ adj, int* __restrict__ offs, int E, int NB, int FB) {
  __shared__ __align__(16) ushort smem[16384];  // As|Bs ; reused as Cs / sort scratch
  int bid = blockIdx.x;
  int tid = threadIdx.x;
  if (bid < FB) {                        // fine sort of bucket `bid` — LDS atomics only
    int b = bid;
    int S = gscan[b * HB];
    int T = (b + 1 < NB) ? gscan[(b + 1) * HB] : E;
    int base = b << BKT_SH;
    int* sdeg = (int*)smem;              // [128]
    int* scur = sdeg + 128;              // [128]
    int* sscn = scur + 128;              // [128]
    if (tid < 128) sdeg[tid] = 0;
    __syncthreads();
    for (int e = S + tid; e < T; e += 256)
      atomicAdd(&sdeg[cs[e] & 127], 1);
    __syncthreads();
    if (tid < 128) sscn[tid] = sdeg[tid];
    __syncthreads();
#pragma unroll
    for (int d = 1; d < 128; d <<= 1) {
      int t = (tid >= d && tid < 128) ? sscn[tid - d] : 0;
      __syncthreads();
      if (tid < 128) sscn[tid] += t;
      __syncthreads();
    }
    if (tid < 128) {
      int excl = sscn[tid] - sdeg[tid];  // exclusive prefix within bucket
      scur[tid] = excl;
      int node = base + tid;
      int Nn = NB << BKT_SH;  (void)Nn;
      if (node < M) offs[node] = S + excl;       // M == N here
    }
    if (tid == 0 && b == NB - 1) offs[M] = E;
    __syncthreads();
    for (int e = S + tid; e < T; e += 256) {
      uint32_t v = cs[e];
      int p = atomicAdd(&scur[v & 127], 1);
      adj[S + p] = (int)(v >> BKT_SH);
    }
    return;
  }
  bid -= FB;
  // XCD-grouping map (bijective, m204): raw id -> work id so the 4 blocks
  // sharing one A-tile all land on the same XCD's L2.
  int TB = (int)gridDim.x - FB;
  int q = TB >> 3, r = TB & 7;
  int xcd = bid & 7, off = bid >> 3;
  int w = (xcd < r) ? xcd * (q + 1) + off : r * (q + 1) + (xcd - r) * q + off;
  int n0 = (w & 3) * 128;
  int m0 = (w >> 2) * 128;

  ushort* As = smem;
  ushort* Bs = smem + 8192;
  int wave = tid >> 6, lane = tid & 63;
  int wm = (wave >> 1) * 64, wn = (wave & 1) * 64;
  int fr = lane & 15, fq = lane >> 4;
  int rsub = lane >> 3;                          // 0..7 (row within 8-row group)
  int ksw = ((lane & 7) ^ rsub) * 8;             // inverse-swizzled k element offset

  floatx4 acc[4][4] = {};

  for (int k0 = 0; k0 < DIN; k0 += 64) {
#pragma unroll
    for (int i = 0; i < 4; i++) {
      int g = wave * 4 + i;                      // 8-row group 0..15
      int ra = g * 8 + rsub;                     // tile row 0..127
      int gm = m0 + ra; if (gm >= M) gm = M - 1; // clamp tail rows
      gload16(A + (size_t)gm * DIN + k0 + ksw, As + g * 512);
      gload16(Bw + (size_t)(n0 + ra) * DIN + k0 + ksw, Bs + g * 512);
    }
    __syncthreads();                             // vmcnt(0) drain + barrier
#pragma unroll
    for (int kk = 0; kk < 2; kk++) {
      bf16x8 af[4], bg[4];
#pragma unroll
      for (int t = 0; t < 4; t++) {
        int ra = wm + t * 16 + fr;
        af[t] = *(const bf16x8*)(As + ra * 64 + (((kk * 4 + fq) ^ (ra & 7)) << 3));
        int rb = wn + t * 16 + fr;
        bg[t] = *(const bf16x8*)(Bs + rb * 64 + (((kk * 4 + fq) ^ (rb & 7)) << 3));
      }
#pragma unroll
      for (int mt = 0; mt < 4; mt++)
#pragma unroll
        for (int nt = 0; nt < 4; nt++)
          acc[mt][nt] = __builtin_amdgcn_mfma_f32_16x16x32_bf16(
              af[mt], bg[nt], acc[mt][nt], 0, 0, 0);
    }
    __syncthreads();
  }

  // epilogue: bias + bf16 -> swizzled LDS C-tile -> coalesced 16B stores
  int rq = fq * 4;
#pragma unroll
  for (int nt = 0; nt < 4; nt++) {
    int col = wn + nt * 16 + fr;
    float bb = bias[n0 + col];
    int c16 = col >> 3;
#pragma unroll
    for (int mt = 0; mt < 4; mt++) {
#pragma unroll
      for (int rr = 0; rr < 4; rr++) {
        int row = wm + mt * 16 + rq + rr;
        smem[row * 128 + (((c16 ^ (row & 7)) << 3) | (col & 7))] =
            f2bf(acc[mt][nt][rr] + bb);
      }
    }
  }
  __syncthreads();
#pragma unroll
  for (int p = 0; p < 8; p++) {
    int idx = p * 256 + tid;
    int row = idx >> 4, cc = idx & 15;
    uint4 v = *(const uint4*)(smem + row * 128 + ((cc ^ (row & 7)) << 3));
    int gm = m0 + row;
    if (gm < M) *(uint4*)(Hb + (size_t)gm * DOUT + n0 + cc * 8) = v;
  }
}

// ---------------- aggregate + mean + expmap0 (one wave per node) ----------------
static __device__ __forceinline__ void accum8(float* acc, uint4 v) {
  acc[0] += __uint_as_float(v.x << 16); acc[1] += __uint_as_float(v.x & 0xFFFF0000u);
  acc[2] += __uint_as_float(v.y << 16); acc[3] += __uint_as_float(v.y & 0xFFFF0000u);
  acc[4] += __uint_as_float(v.z << 16); acc[5] += __uint_as_float(v.z & 0xFFFF0000u);
  acc[6] += __uint_as_float(v.w << 16); acc[7] += __uint_as_float(v.w & 0xFFFF0000u);
}

__global__ __launch_bounds__(256) void aggregate_kernel(const ushort* __restrict__ hb,
                                                        const int* __restrict__ adj,
                                                        const int* __restrict__ offs,
                                                        float* __restrict__ out, int N) {
  int row = blockIdx.x * 4 + (threadIdx.x >> 6);
  if (row >= N) return;
  int lane = threadIdx.x & 63;
  int base = offs[row];
  int dg = offs[row + 1] - base;
  float acc[8] = {0.f, 0.f, 0.f, 0.f, 0.f, 0.f, 0.f, 0.f};
  int j = 0;
  for (; j + 8 <= dg; j += 8) {           // 8 gathers in flight
    int av = adj[base + j + (lane & 7)];  // one load, broadcast via readlane
    uint4 v[8];
#pragma unroll
    for (int qq = 0; qq < 8; qq++) {
      int s = __builtin_amdgcn_readlane(av, qq);
      v[qq] = *(const uint4*)(hb + (size_t)s * DOUT + lane * 8);
    }
#pragma unroll
    for (int qq = 0; qq < 8; qq++) accum8(acc, v[qq]);
  }
  for (; j + 4 <= dg; j += 4) {
    int av = adj[base + j + (lane & 3)];
    uint4 v[4];
#pragma unroll
    for (int qq = 0; qq < 4; qq++) {
      int s = __builtin_amdgcn_readlane(av, qq);
      v[qq] = *(const uint4*)(hb + (size_t)s * DOUT + lane * 8);
    }
#pragma unroll
    for (int qq = 0; qq < 4; qq++) accum8(acc, v[qq]);
  }
  for (; j < dg; j++) {
    int s = __builtin_amdgcn_readfirstlane(adj[base + j]);
    uint4 a = *(const uint4*)(hb + (size_t)s * DOUT + lane * 8);
    accum8(acc, a);
  }
  float inv = 1.0f / fmaxf((float)dg, 1.0f);
  float ss = 0.f;
#pragma unroll
  for (int k = 0; k < 8; k++) ss += acc[k] * acc[k];
#pragma unroll
  for (int m = 32; m >= 1; m >>= 1) ss += __shfl_xor(ss, m, 64);
  float n = fmaxf(inv * sqrtf(ss), 1e-7f);   // ||mean||, clamped like reference
  float sc = tanhf(n) / n * inv;
  f32x4 o0 = {acc[0] * sc, acc[1] * sc, acc[2] * sc, acc[3] * sc};
  f32x4 o1 = {acc[4] * sc, acc[5] * sc, acc[6] * sc, acc[7] * sc};
  float* orow = out + (size_t)row * DOUT + lane * 8;
  // nontemporal: out is write-once; keep L2/L3 for the hb gather working set
  __builtin_nontemporal_store(o0, (f32x4*)orow);
  __builtin_nontemporal_store(o1, (f32x4*)(orow + 4));
}

extern "C" void kernel_launch(void* const* d_in, const int* in_sizes, int n_in,
                              void* d_out, int out_size, void* d_ws, size_t ws_size,
                              hipStream_t stream) {
  const float* x = (const float*)d_in[0];
  const int* src = (const int*)d_in[1];
  const int* dst = (const int*)d_in[2];
  const float* W = (const float*)d_in[3];
  const float* b = (const float*)d_in[4];
  int N = in_sizes[0] / DIN;
  int E = in_sizes[1];
  float* out = (float*)d_out;

  int NB = (N + 127) >> BKT_SH;          // 782 buckets (requires NB <= 1024)
  int L = NB * HB;                       // ghist length

  // workspace layout
  char* ws = (char*)d_ws;
  size_t off = 0;
  ushort* Wbf = (ushort*)(ws + off); off += (size_t)DOUT * DIN * 2;
  ushort* tanb = (ushort*)(ws + off); off += (size_t)N * DIN * 2;
  ushort* hb = (ushort*)(ws + off); off += (size_t)N * DIN * 2;
  off = (off + 255) & ~(size_t)255;
  int* offs = (int*)(ws + off); off += (size_t)(N + 1) * 4;
  off = (off + 255) & ~(size_t)255;
  int* ghist = (int*)(ws + off); off += (size_t)L * 4;
  off = (off + 255) & ~(size_t)255;
  int* gscan = (int*)(ws + off); off += (size_t)L * 4;
  off = (off + 255) & ~(size_t)255;
  int* bsum = (int*)(ws + off); off += 1024 * 4;
  off = (off + 255) & ~(size_t)255;
  uint32_t* cs = (uint32_t*)(ws + off); off += (size_t)E * 4;
  off = (off + 255) & ~(size_t)255;
  int* adj = (int*)(ws + off); off += (size_t)E * 4;

  int logB = (N + 3) >> 2;               // 25000
  int wB = (DOUT * DIN) / 1024;          // 256
  fused1_kernel<<<HB + logB + wB, 256, 0, stream>>>(x, tanb, W, Wbf, dst, ghist,
                                                    N, E, NB);

  scan1_kernel<<<NB, 256, 0, stream>>>(ghist, gscan, bsum, L);   // L = NB*256
  scan2_kernel<<<1, 1024, 0, stream>>>(bsum, NB);
  scan3_kernel<<<NB, 256, 0, stream>>>(gscan, bsum, L);

  cscatter_kernel<<<HB, 256, 0, stream>>>(src, dst, gscan, cs, E, NB);

  int MB = (N + 127) >> 7;               // 782 m-tiles
  int FB = NB;                           // fine-sort blocks lead the gemm grid
  gemmfill_kernel<<<FB + 4 * MB, 256, 0, stream>>>(tanb, Wbf, b, hb, N,
                                                   gscan, cs, adj, offs, E, NB, FB);

  aggregate_kernel<<<(N + 3) / 4, 256, 0, stream>>>(hb, adj, offs, out, N);
}

// Round 4
// 589.960 us; speedup vs baseline: 1.2599x; 1.0009x over previous
//
#include <hip/hip_runtime.h>
#include <stdint.h>

#define DIN 512
#define DOUT 512
#define HB 256        // histogram / coarse-scatter blocks
#define BKT_SH 7      // bucket = dst >> 7  (128 nodes per bucket; NB <= 1024 for N <= 131072)

typedef short bf16x8 __attribute__((ext_vector_type(8)));
typedef float floatx4 __attribute__((ext_vector_type(4)));
typedef float f32x4 __attribute__((ext_vector_type(4)));

static __device__ __forceinline__ ushort f2bf(float f) {
  uint32_t u = __float_as_uint(f);
  u += 0x7FFFu + ((u >> 16) & 1u);   // RTNE; values are finite/normal here
  return (ushort)(u >> 16);
}

// async global->LDS, 16B per lane; LDS dest is wave-uniform base + lane*16
static __device__ __forceinline__ void gload16(const ushort* g, ushort* l) {
  __builtin_amdgcn_global_load_lds(
      (const __attribute__((address_space(1))) unsigned int*)g,
      (__attribute__((address_space(3))) unsigned int*)l, 16, 0, 0);
}

// ---------------- fused: coarse-hist (LDS atomics) | logmap0+bf16 | W->bf16 ------
__global__ __launch_bounds__(256) void fused1_kernel(
    const float* __restrict__ x, ushort* __restrict__ tanb,
    const float* __restrict__ W, ushort* __restrict__ Wbf,
    const int* __restrict__ dst, int* __restrict__ ghist, int N, int E, int NB) {
  __shared__ int hist[1024];
  int bid = blockIdx.x;
  int tx = threadIdx.x;
  if (bid < HB) {                        // per-block private bucket histogram
    for (int i = tx; i < NB; i += 256) hist[i] = 0;
    __syncthreads();
    int EPB = (E + HB - 1) / HB;
    int e0 = bid * EPB;
    int e1 = e0 + EPB; if (e1 > E) e1 = E;
    for (int e = e0 + tx; e < e1; e += 256)
      atomicAdd(&hist[dst[e] >> BKT_SH], 1);       // LDS atomic — no L2 round trip
    __syncthreads();
    for (int b = tx; b < NB; b += 256)
      ghist[b * HB + bid] = hist[b];               // bucket-major for the scan
    return;
  }
  bid -= HB;
  int logB = (N + 3) >> 2;
  if (bid < logB) {                      // logmap0 + cast (memory-bound)
    int row = bid * 4 + (tx >> 6);
    if (row >= N) return;
    int lane = tx & 63;
    const f32x4* xr = (const f32x4*)(x + (size_t)row * DIN);
    f32x4 v0 = __builtin_nontemporal_load(xr + lane * 2);      // x read once
    f32x4 v1 = __builtin_nontemporal_load(xr + lane * 2 + 1);
    float ss = v0[0]*v0[0] + v0[1]*v0[1] + v0[2]*v0[2] + v0[3]*v0[3] +
               v1[0]*v1[0] + v1[1]*v1[1] + v1[2]*v1[2] + v1[3]*v1[3];
#pragma unroll
    for (int m = 32; m >= 1; m >>= 1) ss += __shfl_xor(ss, m, 64);
    float n = sqrtf(ss);
    float nc = fminf(fmaxf(n, 1e-7f), 1.0f - 1e-7f);
    float scale = atanhf(nc) / nc;
    union { ushort s[8]; uint4 v; } o;
    o.s[0] = f2bf(v0[0] * scale); o.s[1] = f2bf(v0[1] * scale);
    o.s[2] = f2bf(v0[2] * scale); o.s[3] = f2bf(v0[3] * scale);
    o.s[4] = f2bf(v1[0] * scale); o.s[5] = f2bf(v1[1] * scale);
    o.s[6] = f2bf(v1[2] * scale); o.s[7] = f2bf(v1[3] * scale);
    *(uint4*)(tanb + (size_t)row * DIN + lane * 8) = o.v;
    return;
  }
  bid -= logB;                           // W fp32 -> bf16 (256 blocks)
  int i = bid * 1024 + tx * 4;
  float4 w4 = *(const float4*)(W + i);
  ushort4 o4;
  o4.x = f2bf(w4.x); o4.y = f2bf(w4.y); o4.z = f2bf(w4.z); o4.w = f2bf(w4.w);
  *(ushort4*)(Wbf + i) = o4;
}

// ---------------- scan: per-block exclusive (scan1) + block offsets (scan2) -----
// Bucket b start index == bsum[b] (scan1 block b covers exactly bucket b).
__global__ __launch_bounds__(256) void scan1_kernel(const int* __restrict__ in,
                                                    int* __restrict__ outp,
                                                    int* __restrict__ bsum, int L) {
  __shared__ int s[256];
  int tx = threadIdx.x;
  int i = blockIdx.x * 256 + tx;
  int v = (i < L) ? in[i] : 0;
  s[tx] = v;
  __syncthreads();
#pragma unroll
  for (int d = 1; d < 256; d <<= 1) {
    int t = (tx >= d) ? s[tx - d] : 0;
    __syncthreads();
    s[tx] += t;
    __syncthreads();
  }
  if (i < L) outp[i] = s[tx] - v;            // exclusive within block
  if (tx == 255) bsum[blockIdx.x] = s[255];
}

__global__ __launch_bounds__(1024) void scan2_kernel(int* __restrict__ bsum, int B) {
  __shared__ int s[1024];
  int tx = threadIdx.x;
  int v = (tx < B) ? bsum[tx] : 0;
  s[tx] = v;
  __syncthreads();
#pragma unroll
  for (int d = 1; d < 1024; d <<= 1) {
    int t = (tx >= d) ? s[tx - d] : 0;
    __syncthreads();
    s[tx] += t;
    __syncthreads();
  }
  if (tx < B) bsum[tx] = s[tx] - v;          // exclusive block offsets
}

// ---------------- coarse scatter: edges -> bucket-contiguous cs[] ---------------
// cs value packs (src << BKT_SH) | (dst & 127); valid for N < 2^25.
__global__ __launch_bounds__(256) void cscatter_kernel(
    const int* __restrict__ src, const int* __restrict__ dst,
    const int* __restrict__ gscan, const int* __restrict__ bsum,
    uint32_t* __restrict__ cs, int E, int NB) {
  __shared__ int lcur[1024];
  int j = blockIdx.x, tx = threadIdx.x;
  for (int b = tx; b < NB; b += 256) lcur[b] = gscan[b * HB + j] + bsum[b];
  __syncthreads();
  int EPB = (E + HB - 1) / HB;
  int e0 = j * EPB;
  int e1 = e0 + EPB; if (e1 > E) e1 = E;
  for (int e = e0 + tx; e < e1; e += 256) {
    int d = dst[e];
    int p = atomicAdd(&lcur[d >> BKT_SH], 1);      // LDS atomic with return
    cs[p] = ((uint32_t)src[e] << BKT_SH) | (uint32_t)(d & ((1 << BKT_SH) - 1));
  }
}

// ---------------- GEMM (m97 structure) + per-bucket fine counting sort ----------
// Hb[m][n] = bf16( sum_k tan[m][k]*W[n][k] + b[n] )
__global__ __launch_bounds__(256) void gemmfill_kernel(
    const ushort* __restrict__ A, const ushort* __restrict__ Bw,
    const float* __restrict__ bias, ushort* __restrict__ Hb, int M,
    const int* __restrict__ bsum, const uint32_t* __restrict__ cs,
    int* __restrict__ adj, int* __restrict__ offs, int E, int NB, int FB) {
  __shared__ __align__(16) ushort smem[16384];  // As|Bs ; reused as Cs / sort scratch
  int bid = blockIdx.x;
  int tid = threadIdx.x;
  if (bid < FB) {                        // fine sort of bucket `bid` — LDS atomics only
    int b = bid;
    int S = bsum[b];
    int T = (b + 1 < NB) ? bsum[b + 1] : E;
    int base = b << BKT_SH;
    int* sdeg = (int*)smem;              // [128]
    int* scur = sdeg + 128;              // [128]
    int* sscn = scur + 128;              // [128]
    if (tid < 128) sdeg[tid] = 0;
    __syncthreads();
    for (int e = S + tid; e < T; e += 256)
      atomicAdd(&sdeg[cs[e] & 127], 1);
    __syncthreads();
    if (tid < 128) sscn[tid] = sdeg[tid];
    __syncthreads();
#pragma unroll
    for (int d = 1; d < 128; d <<= 1) {
      int t = (tid >= d && tid < 128) ? sscn[tid - d] : 0;
      __syncthreads();
      if (tid < 128) sscn[tid] += t;
      __syncthreads();
    }
    if (tid < 128) {
      int excl = sscn[tid] - sdeg[tid];  // exclusive prefix within bucket
      scur[tid] = excl;
      int node = base + tid;
      if (node < M) offs[node] = S + excl;       // M == N here
    }
    if (tid == 0 && b == NB - 1) offs[M] = E;
    __syncthreads();
    for (int e = S + tid; e < T; e += 256) {
      uint32_t v = cs[e];
      int p = atomicAdd(&scur[v & 127], 1);
      adj[S + p] = (int)(v >> BKT_SH);
    }
    return;
  }
  bid -= FB;
  // XCD-grouping map (bijective, m204): raw id -> work id so the 4 blocks
  // sharing one A-tile all land on the same XCD's L2.
  int TB = (int)gridDim.x - FB;
  int q = TB >> 3, r = TB & 7;
  int xcd = bid & 7, off = bid >> 3;
  int w = (xcd < r) ? xcd * (q + 1) + off : r * (q + 1) + (xcd - r) * q + off;
  int n0 = (w & 3) * 128;
  int m0 = (w >> 2) * 128;

  ushort* As = smem;
  ushort* Bs = smem + 8192;
  int wave = tid >> 6, lane = tid & 63;
  int wm = (wave >> 1) * 64, wn = (wave & 1) * 64;
  int fr = lane & 15, fq = lane >> 4;
  int rsub = lane >> 3;                          // 0..7 (row within 8-row group)
  int ksw = ((lane & 7) ^ rsub) * 8;             // inverse-swizzled k element offset

  floatx4 acc[4][4] = {};

  for (int k0 = 0; k0 < DIN; k0 += 64) {
#pragma unroll
    for (int i = 0; i < 4; i++) {
      int g = wave * 4 + i;                      // 8-row group 0..15
      int ra = g * 8 + rsub;                     // tile row 0..127
      int gm = m0 + ra; if (gm >= M) gm = M - 1; // clamp tail rows
      gload16(A + (size_t)gm * DIN + k0 + ksw, As + g * 512);
      gload16(Bw + (size_t)(n0 + ra) * DIN + k0 + ksw, Bs + g * 512);
    }
    __syncthreads();                             // vmcnt(0) drain + barrier
#pragma unroll
    for (int kk = 0; kk < 2; kk++) {
      bf16x8 af[4], bg[4];
#pragma unroll
      for (int t = 0; t < 4; t++) {
        int ra = wm + t * 16 + fr;
        af[t] = *(const bf16x8*)(As + ra * 64 + (((kk * 4 + fq) ^ (ra & 7)) << 3));
        int rb = wn + t * 16 + fr;
        bg[t] = *(const bf16x8*)(Bs + rb * 64 + (((kk * 4 + fq) ^ (rb & 7)) << 3));
      }
#pragma unroll
      for (int mt = 0; mt < 4; mt++)
#pragma unroll
        for (int nt = 0; nt < 4; nt++)
          acc[mt][nt] = __builtin_amdgcn_mfma_f32_16x16x32_bf16(
              af[mt], bg[nt], acc[mt][nt], 0, 0, 0);
    }
    __syncthreads();
  }

  // epilogue: bias + bf16 -> swizzled LDS C-tile -> coalesced 16B stores
  int rq = fq * 4;
#pragma unroll
  for (int nt = 0; nt < 4; nt++) {
    int col = wn + nt * 16 + fr;
    float bb = bias[n0 + col];
    int c16 = col >> 3;
#pragma unroll
    for (int mt = 0; mt < 4; mt++) {
#pragma unroll
      for (int rr = 0; rr < 4; rr++) {
        int row = wm + mt * 16 + rq + rr;
        smem[row * 128 + (((c16 ^ (row & 7)) << 3) | (col & 7))] =
            f2bf(acc[mt][nt][rr] + bb);
      }
    }
  }
  __syncthreads();
#pragma unroll
  for (int p = 0; p < 8; p++) {
    int idx = p * 256 + tid;
    int row = idx >> 4, cc = idx & 15;
    uint4 v = *(const uint4*)(smem + row * 128 + ((cc ^ (row & 7)) << 3));
    int gm = m0 + row;
    if (gm < M) *(uint4*)(Hb + (size_t)gm * DOUT + n0 + cc * 8) = v;
  }
}

// ---------------- aggregate + mean + expmap0 (two rows per wave) ----------------
static __device__ __forceinline__ void accum8(float* acc, uint4 v) {
  acc[0] += __uint_as_float(v.x << 16); acc[1] += __uint_as_float(v.x & 0xFFFF0000u);
  acc[2] += __uint_as_float(v.y << 16); acc[3] += __uint_as_float(v.y & 0xFFFF0000u);
  acc[4] += __uint_as_float(v.z << 16); acc[5] += __uint_as_float(v.z & 0xFFFF0000u);
  acc[6] += __uint_as_float(v.w << 16); acc[7] += __uint_as_float(v.w & 0xFFFF0000u);
}

static __device__ __forceinline__ void finish_row(float* acc, int dg, int row,
                                                  int lane, float* __restrict__ out) {
  float inv = 1.0f / fmaxf((float)dg, 1.0f);
  float ss = 0.f;
#pragma unroll
  for (int k = 0; k < 8; k++) ss += acc[k] * acc[k];
#pragma unroll
  for (int m = 32; m >= 1; m >>= 1) ss += __shfl_xor(ss, m, 64);
  float n = fmaxf(inv * sqrtf(ss), 1e-7f);   // ||mean||, clamped like reference
  float sc = tanhf(n) / n * inv;
  f32x4 o0 = {acc[0] * sc, acc[1] * sc, acc[2] * sc, acc[3] * sc};
  f32x4 o1 = {acc[4] * sc, acc[5] * sc, acc[6] * sc, acc[7] * sc};
  float* orow = out + (size_t)row * DOUT + lane * 8;
  // nontemporal: out is write-once; keep L2/L3 for the hb gather working set
  __builtin_nontemporal_store(o0, (f32x4*)orow);
  __builtin_nontemporal_store(o1, (f32x4*)(orow + 4));
}

__global__ __launch_bounds__(256) void aggregate_kernel(const ushort* __restrict__ hb,
                                                        const int* __restrict__ adj,
                                                        const int* __restrict__ offs,
                                                        float* __restrict__ out, int N) {
  int wid = blockIdx.x * 4 + (threadIdx.x >> 6);
  int r0 = wid * 2;
  if (r0 >= N) return;
  int r1 = r0 + 1;
  int has1 = (r1 < N);
  int lane = threadIdx.x & 63;
  int b0 = offs[r0];
  int e0 = offs[r0 + 1];
  int e1 = has1 ? offs[r0 + 2] : e0;   // offs[r1] == e0 (contiguous CSR)
  int dg0 = e0 - b0;
  int dg1 = e1 - e0;
  int c0 = dg0 < 64 ? dg0 : 64;        // adjacency preloaded into lanes (deg<=64 path)
  int c1 = dg1 < 64 ? dg1 : 64;
  int av0 = (lane < c0) ? adj[b0 + lane] : 0;
  int av1 = (lane < c1) ? adj[e0 + lane] : 0;
  float acc0[8] = {0.f, 0.f, 0.f, 0.f, 0.f, 0.f, 0.f, 0.f};
  float acc1[8] = {0.f, 0.f, 0.f, 0.f, 0.f, 0.f, 0.f, 0.f};
  int mx = c0 > c1 ? c0 : c1;
  for (int j = 0; j < mx; j += 8) {    // two rows' batches of 8 in flight together
    uint4 v0[8], v1[8];
    int n0 = c0 - j; n0 = n0 < 0 ? 0 : (n0 > 8 ? 8 : n0);
    int n1 = c1 - j; n1 = n1 < 0 ? 0 : (n1 > 8 ? 8 : n1);
#pragma unroll
    for (int q = 0; q < 8; q++)
      if (q < n0) {                    // wave-uniform predicate; loads all issue
        int s = __builtin_amdgcn_readlane(av0, j + q);
        v0[q] = *(const uint4*)(hb + (size_t)s * DOUT + lane * 8);
      }
#pragma unroll
    for (int q = 0; q < 8; q++)
      if (q < n1) {
        int s = __builtin_amdgcn_readlane(av1, j + q);
        v1[q] = *(const uint4*)(hb + (size_t)s * DOUT + lane * 8);
      }
#pragma unroll
    for (int q = 0; q < 8; q++) if (q < n0) accum8(acc0, v0[q]);
#pragma unroll
    for (int q = 0; q < 8; q++) if (q < n1) accum8(acc1, v1[q]);
  }
  for (int j = 64; j < dg0; j++) {     // deg>64 fallback (improbable at mean 10)
    int s = __builtin_amdgcn_readfirstlane(adj[b0 + j]);
    accum8(acc0, *(const uint4*)(hb + (size_t)s * DOUT + lane * 8));
  }
  for (int j = 64; j < dg1; j++) {
    int s = __builtin_amdgcn_readfirstlane(adj[e0 + j]);
    accum8(acc1, *(const uint4*)(hb + (size_t)s * DOUT + lane * 8));
  }
  finish_row(acc0, dg0, r0, lane, out);
  if (has1) finish_row(acc1, dg1, r1, lane, out);
}

extern "C" void kernel_launch(void* const* d_in, const int* in_sizes, int n_in,
                              void* d_out, int out_size, void* d_ws, size_t ws_size,
                              hipStream_t stream) {
  const float* x = (const float*)d_in[0];
  const int* src = (const int*)d_in[1];
  const int* dst = (const int*)d_in[2];
  const float* W = (const float*)d_in[3];
  const float* b = (const float*)d_in[4];
  int N = in_sizes[0] / DIN;
  int E = in_sizes[1];
  float* out = (float*)d_out;

  int NB = (N + 127) >> BKT_SH;          // 782 buckets (requires NB <= 1024)
  int L = NB * HB;                       // ghist length

  // workspace layout
  char* ws = (char*)d_ws;
  size_t off = 0;
  ushort* Wbf = (ushort*)(ws + off); off += (size_t)DOUT * DIN * 2;
  ushort* tanb = (ushort*)(ws + off); off += (size_t)N * DIN * 2;
  ushort* hb = (ushort*)(ws + off); off += (size_t)N * DIN * 2;
  off = (off + 255) & ~(size_t)255;
  int* offs = (int*)(ws + off); off += (size_t)(N + 1) * 4;
  off = (off + 255) & ~(size_t)255;
  int* ghist = (int*)(ws + off); off += (size_t)L * 4;
  off = (off + 255) & ~(size_t)255;
  int* gscan = (int*)(ws + off); off += (size_t)L * 4;
  off = (off + 255) & ~(size_t)255;
  int* bsum = (int*)(ws + off); off += 1024 * 4;
  off = (off + 255) & ~(size_t)255;
  uint32_t* cs = (uint32_t*)(ws + off); off += (size_t)E * 4;
  off = (off + 255) & ~(size_t)255;
  int* adj = (int*)(ws + off); off += (size_t)E * 4;

  int logB = (N + 3) >> 2;               // 25000
  int wB = (DOUT * DIN) / 1024;          // 256
  fused1_kernel<<<HB + logB + wB, 256, 0, stream>>>(x, tanb, W, Wbf, dst, ghist,
                                                    N, E, NB);

  scan1_kernel<<<NB, 256, 0, stream>>>(ghist, gscan, bsum, L);   // L = NB*256
  scan2_kernel<<<1, 1024, 0, stream>>>(bsum, NB);

  cscatter_kernel<<<HB, 256, 0, stream>>>(src, dst, gscan, bsum, cs, E, NB);

  int MB = (N + 127) >> 7;               // 782 m-tiles
  int FB = NB;                           // fine-sort blocks lead the gemm grid
  gemmfill_kernel<<<FB + 4 * MB, 256, 0, stream>>>(tanb, Wbf, b, hb, N,
                                                   bsum, cs, adj, offs, E, NB, FB);

  aggregate_kernel<<<(N + 7) / 8, 256, 0, stream>>>(hb, adj, offs, out, N);
}